// Round 2
// baseline (2971.767 us; speedup 1.0000x reference)
//
#include <hip/hip_runtime.h>
#include <math.h>

#define TT 64
#define BB 64
#define DD 512
#define HH 512
#define G4 2048
#define OO 128

typedef unsigned short us16;
typedef __attribute__((ext_vector_type(8))) short bf16x8;
typedef __attribute__((ext_vector_type(4))) float f32x4;

__device__ __forceinline__ unsigned pk_bf16(float lo, float hi) {
  unsigned r;
  asm volatile("v_cvt_pk_bf16_f32 %0, %1, %2" : "=v"(r) : "v"(lo), "v"(hi));
  return r;
}

__device__ __forceinline__ void gload_lds16(const void* g, void* l) {
  __builtin_amdgcn_global_load_lds(
      (const __attribute__((address_space(1))) unsigned int*)g,
      (__attribute__((address_space(3))) unsigned int*)l, 16, 0, 0);
}

__device__ __forceinline__ float sigm(float v) { return 1.f / (1.f + expf(-v)); }

// ============================================================================
// Phase A: G[t,b,j] = x_t @ Wih_t^T + b_ih + b_hh   via bf16 MFMA
// grid (16 j-tiles of 128, 64 t) x 256 threads. Tile 64b x 128j, K-chunk 64.
// LDS bf16, XOR chunk-swizzle p = c ^ (row&7) on both write and read.
// ============================================================================
__global__ __launch_bounds__(256) void phaseA_mfma(
    const float* __restrict__ x, const float* __restrict__ wih,
    const float* __restrict__ bih, const float* __restrict__ bhh,
    float* __restrict__ Gb) {
  __shared__ us16 xa[2][64][64];     // 16 KB
  __shared__ us16 wbuf[2][128][64];  // 32 KB
  const int tid = threadIdx.x;
  const int t = blockIdx.y;
  const int j0 = blockIdx.x * 128;
  const int wv = tid >> 6, lane = tid & 63;
  const int wm = wv & 1, wn = wv >> 1;
  const float* xb = x + (size_t)t * (BB * DD);
  const float* wg = wih + (size_t)t * (G4 * DD) + (size_t)j0 * DD;

  float4 xr[2][2], wr[4][2];
  int xrow[2], xc[2], wrow[4], wc[4];
#pragma unroll
  for (int i = 0; i < 2; i++) { int cid = tid + i * 256; xrow[i] = cid >> 3; xc[i] = cid & 7; }
#pragma unroll
  for (int i = 0; i < 4; i++) { int cid = tid + i * 256; wrow[i] = cid >> 3; wc[i] = cid & 7; }

  auto loadx = [&](int k0) {
#pragma unroll
    for (int i = 0; i < 2; i++) {
      const float* p = xb + xrow[i] * DD + k0 + xc[i] * 8;
      xr[i][0] = *(const float4*)p; xr[i][1] = *(const float4*)(p + 4);
    }
  };
  auto loadw = [&](int k0) {
#pragma unroll
    for (int i = 0; i < 4; i++) {
      const float* p = wg + (size_t)wrow[i] * DD + k0 + wc[i] * 8;
      wr[i][0] = *(const float4*)p; wr[i][1] = *(const float4*)(p + 4);
    }
  };
  auto store = [&](int buf) {
#pragma unroll
    for (int i = 0; i < 2; i++) {
      uint4 u;
      u.x = pk_bf16(xr[i][0].x, xr[i][0].y); u.y = pk_bf16(xr[i][0].z, xr[i][0].w);
      u.z = pk_bf16(xr[i][1].x, xr[i][1].y); u.w = pk_bf16(xr[i][1].z, xr[i][1].w);
      int p = xc[i] ^ (xrow[i] & 7);
      *(uint4*)&xa[buf][xrow[i]][p * 8] = u;
    }
#pragma unroll
    for (int i = 0; i < 4; i++) {
      uint4 u;
      u.x = pk_bf16(wr[i][0].x, wr[i][0].y); u.y = pk_bf16(wr[i][0].z, wr[i][0].w);
      u.z = pk_bf16(wr[i][1].x, wr[i][1].y); u.w = pk_bf16(wr[i][1].z, wr[i][1].w);
      int p = wc[i] ^ (wrow[i] & 7);
      *(uint4*)&wbuf[buf][wrow[i]][p * 8] = u;
    }
  };

  loadx(0); loadw(0); store(0);
  __syncthreads();

  f32x4 zero = {0.f, 0.f, 0.f, 0.f};
  f32x4 acc[2][4];
#pragma unroll
  for (int mt = 0; mt < 2; mt++)
#pragma unroll
    for (int nt = 0; nt < 4; nt++) acc[mt][nt] = zero;

  for (int s = 0; s < 8; s++) {
    const int nb = s & 1;
    if (s < 7) { loadx((s + 1) * 64); loadw((s + 1) * 64); }
#pragma unroll
    for (int ks = 0; ks < 2; ks++) {
      const int cc = ks * 4 + (lane >> 4);
      bf16x8 a[2], b[4];
#pragma unroll
      for (int mt = 0; mt < 2; mt++) {
        int r = wm * 32 + mt * 16 + (lane & 15);
        a[mt] = *(const bf16x8*)&xa[nb][r][(cc ^ (r & 7)) * 8];
      }
#pragma unroll
      for (int nt = 0; nt < 4; nt++) {
        int r = wn * 64 + nt * 16 + (lane & 15);
        b[nt] = *(const bf16x8*)&wbuf[nb][r][(cc ^ (r & 7)) * 8];
      }
#pragma unroll
      for (int mt = 0; mt < 2; mt++)
#pragma unroll
        for (int nt = 0; nt < 4; nt++)
          acc[mt][nt] = __builtin_amdgcn_mfma_f32_16x16x32_bf16(a[mt], b[nt], acc[mt][nt], 0, 0, 0);
    }
    __syncthreads();
    if (s < 7) store(nb ^ 1);
    __syncthreads();
  }

  // epilogue: add biases, write G (fp32)
  float bias[4]; int jn[4];
#pragma unroll
  for (int nt = 0; nt < 4; nt++) {
    jn[nt] = j0 + wn * 64 + nt * 16 + (lane & 15);
    bias[nt] = bih[t * G4 + jn[nt]] + bhh[t * G4 + jn[nt]];
  }
#pragma unroll
  for (int mt = 0; mt < 2; mt++)
#pragma unroll
    for (int nt = 0; nt < 4; nt++)
#pragma unroll
      for (int e = 0; e < 4; e++) {
        int brow = wm * 32 + mt * 16 + (lane >> 4) * 4 + e;
        Gb[((size_t)t * BB + brow) * G4 + jn[nt]] = acc[mt][nt][e] + bias[nt];
      }
}

// ============================================================================
// Persistent LSTM stepper: 256 blocks (bh = bid&1 batch-half of 32,
// ug = bid>>1 unit-group of 4 units -> 16 gate rows), 256 threads (4 waves).
// Per step: grid barrier -> stage h-half (bf16, global_load_lds, swizzled)
//           -> 8x mfma 16x16x32 per wave (k-split 2, m-split 2)
//           -> LDS partial sum -> epilogue by wave0 (c fp32, h bf16 ping-pong)
// Whh slab for t+1 prefetched into regs before the barrier spin.
// ============================================================================
__global__ __launch_bounds__(256) void lstm_persist(
    const float* __restrict__ whh, const float* __restrict__ Gb,
    const int* __restrict__ lengths, us16* __restrict__ hb,
    float* __restrict__ cbuf, float* __restrict__ hf,
    unsigned* __restrict__ bar) {
  __shared__ us16 h_lds[32][512];   // 32 KB
  __shared__ us16 w_lds[16][512];   // 16 KB
  __shared__ float gm[2][16][36];   // 4.6 KB, padded rows

  const int tid = threadIdx.x, bid = blockIdx.x;
  const int bh = bid & 1, ug = bid >> 1;
  const int wv = tid >> 6, lane = tid & 63;
  const int wm = wv & 1, kq = wv >> 1;

  // prefetch coords: 1024 16B-chunks of the 16 rows x 512 k fp32 slab
  int pr[4], pc[4]; size_t psrc[4];
#pragma unroll
  for (int i = 0; i < 4; i++) {
    int cid = tid + i * 256; pr[i] = cid >> 6; pc[i] = cid & 63;
    int ri = pr[i];
    int j = (ri >> 2) * 512 + ug * 4 + (ri & 3);  // gate row in Whh
    psrc[i] = (size_t)j * HH + (size_t)pc[i] * 8;
  }
  float4 pf[4][2];
  auto pref = [&](int tt) {
    const float* wt = whh + (size_t)tt * (G4 * HH);
#pragma unroll
    for (int i = 0; i < 4; i++) {
      pf[i][0] = *(const float4*)(wt + psrc[i]);
      pf[i][1] = *(const float4*)(wt + psrc[i] + 4);
    }
  };
  auto storew = [&]() {
#pragma unroll
    for (int i = 0; i < 4; i++) {
      uint4 u;
      u.x = pk_bf16(pf[i][0].x, pf[i][0].y); u.y = pk_bf16(pf[i][0].z, pf[i][0].w);
      u.z = pk_bf16(pf[i][1].x, pf[i][1].y); u.w = pk_bf16(pf[i][1].z, pf[i][1].w);
      int p = pc[i] ^ (pr[i] & 7);
      *(uint4*)&w_lds[pr[i]][p * 8] = u;
    }
  };

  const int mylen = (tid < 32) ? lengths[bh * 32 + tid] : 0;

  pref(0); storew();
  __syncthreads();

  for (int t = 0; t < TT; t++) {
    pref(t + 1 < TT ? t + 1 : TT - 1);        // in flight across the spin
    __builtin_amdgcn_sched_barrier(0);
    if (tid == 0) {
      while (__hip_atomic_load(&bar[256], __ATOMIC_ACQUIRE, __HIP_MEMORY_SCOPE_AGENT) <
             (unsigned)(8 * t))
        __builtin_amdgcn_s_sleep(2);
    }
    __syncthreads();
    __threadfence();   // acquire: invalidate L1 so staged h is fresh

    // stage h half (bf16) into LDS, swizzle-consistent source addressing
    const us16* hsrc = hb + (size_t)(t & 1) * (BB * HH) + (size_t)bh * 32 * HH;
    {
      char* lbase = (char*)&h_lds[0][0];
#pragma unroll
      for (int i = 0; i < 8; i++) {
        int base = wv * 512 + i * 64;
        int r = base >> 6;                       // one row per instruction
        const us16* g = hsrc + r * HH + ((lane ^ (r & 7)) * 8);
        gload_lds16(g, lbase + (size_t)base * 16);
      }
    }
    __syncthreads();   // drains vmcnt+lgkm: h_lds ready

    // MFMA: C[b=32][ri=16] split: wm -> b-16-half, kq -> k-256-half
    f32x4 acc = {0.f, 0.f, 0.f, 0.f};
    const int mrow = wm * 16 + (lane & 15);
    const int nrow = lane & 15;
    const int klg = lane >> 4;
#pragma unroll
    for (int s = 0; s < 8; s++) {
      int c = kq * 32 + s * 4 + klg;
      bf16x8 a = *(const bf16x8*)&h_lds[mrow][(c ^ (mrow & 7)) * 8];
      bf16x8 b = *(const bf16x8*)&w_lds[nrow][(c ^ (nrow & 7)) * 8];
      acc = __builtin_amdgcn_mfma_f32_16x16x32_bf16(a, b, acc, 0, 0, 0);
    }
    *(f32x4*)&gm[kq][lane & 15][wm * 16 + klg * 4] = acc;
    __syncthreads();

    if (tid < 32) {  // epilogue: all h-stores from wave 0
      int b = tid, bg = bh * 32 + b;
      const float* gbp = &Gb[((size_t)t * BB + bg) * G4 + ug * 4];
      f32x4 gi = *(const f32x4*)(gbp + 0 * 512);
      f32x4 gf = *(const f32x4*)(gbp + 1 * 512);
      f32x4 gg = *(const f32x4*)(gbp + 2 * 512);
      f32x4 go = *(const f32x4*)(gbp + 3 * 512);
      f32x4 cv = *(const f32x4*)&cbuf[(size_t)bg * HH + ug * 4];
      float hvv[4];
#pragma unroll
      for (int u = 0; u < 4; u++) {
        float vi = gi[u] + gm[0][0 * 4 + u][b] + gm[1][0 * 4 + u][b];
        float vf = gf[u] + gm[0][1 * 4 + u][b] + gm[1][1 * 4 + u][b];
        float vg = gg[u] + gm[0][2 * 4 + u][b] + gm[1][2 * 4 + u][b];
        float vo = go[u] + gm[0][3 * 4 + u][b] + gm[1][3 * 4 + u][b];
        float cn = sigm(vf) * cv[u] + sigm(vi) * tanhf(vg);
        cv[u] = cn;
        hvv[u] = sigm(vo) * tanhf(cn);
      }
      *(f32x4*)&cbuf[(size_t)bg * HH + ug * 4] = cv;
      us16* hdst = hb + (size_t)((t + 1) & 1) * (BB * HH) + (size_t)bg * HH + ug * 4;
      uint2 hu; hu.x = pk_bf16(hvv[0], hvv[1]); hu.y = pk_bf16(hvv[2], hvv[3]);
      *(uint2*)hdst = hu;
      if (mylen - 1 == t) {
        f32x4 hv4 = {hvv[0], hvv[1], hvv[2], hvv[3]};
        *(f32x4*)&hf[(size_t)bg * HH + ug * 4] = hv4;
      }
    }
    storew();          // w_lds <- prefetched t+1 slab (all waves past MFMA)
    __syncthreads();
    if (tid == 0) {    // same wave as all h/c/hf stores -> ordered release
      __threadfence();
      unsigned grp = bid & 7;
      unsigned old = __hip_atomic_fetch_add(&bar[grp * 32], 1u, __ATOMIC_ACQ_REL,
                                            __HIP_MEMORY_SCOPE_AGENT);
      if (old == 32u * (t + 1) - 1u)
        __hip_atomic_fetch_add(&bar[256], 1u, __ATOMIC_ACQ_REL, __HIP_MEMORY_SCOPE_AGENT);
    }
  }
}

// ============================================================================
// Final: logits = hf @ w_ho^T + b_ho, then log_softmax
// ============================================================================
__global__ __launch_bounds__(128) void finalK(const float* __restrict__ hf,
                                              const float* __restrict__ who,
                                              const float* __restrict__ bho,
                                              float* __restrict__ out) {
  int b = blockIdx.x, o = threadIdx.x;
  const float* h = hf + b * HH;
  const float* w = who + o * HH;
  float s = bho[o];
#pragma unroll 4
  for (int k = 0; k < HH; k += 4) {
    float4 hv = *(const float4*)(h + k);
    float4 wv = *(const float4*)(w + k);
    s += hv.x * wv.x + hv.y * wv.y + hv.z * wv.z + hv.w * wv.w;
  }
  __shared__ float red[2];
  __shared__ float red2[2];
  float m = s;
#pragma unroll
  for (int msk = 32; msk; msk >>= 1) m = fmaxf(m, __shfl_xor(m, msk));
  int wave = o >> 6;
  if ((o & 63) == 0) red[wave] = m;
  __syncthreads();
  m = fmaxf(red[0], red[1]);
  float e = expf(s - m);
#pragma unroll
  for (int msk = 32; msk; msk >>= 1) e += __shfl_xor(e, msk);
  if ((o & 63) == 0) red2[wave] = e;
  __syncthreads();
  float sum = red2[0] + red2[1];
  out[b * OO + o] = (s - m) - logf(sum);
}

extern "C" void kernel_launch(void* const* d_in, const int* in_sizes, int n_in,
                              void* d_out, int out_size, void* d_ws, size_t ws_size,
                              hipStream_t stream) {
  const float* x = (const float*)d_in[0];
  const float* wih = (const float*)d_in[1];
  const float* whh = (const float*)d_in[2];
  const float* bih = (const float*)d_in[3];
  const float* bhh = (const float*)d_in[4];
  const float* who = (const float*)d_in[5];
  const float* bho = (const float*)d_in[6];
  const int* lengths = (const int*)d_in[7];
  float* out = (float*)d_out;

  char* ws = (char*)d_ws;
  float* Gb = (float*)ws;                               // 33,554,432 B
  us16* hb = (us16*)(ws + 33554432);                    // 2 x 65,536 B (bf16 ping-pong)
  float* cb = (float*)(ws + 33554432 + 131072);         // 131,072 B
  unsigned* bar = (unsigned*)(ws + 33554432 + 262144);  // 4,096 B
  float* hf = (float*)(ws + 33554432 + 266240);         // 131,072 B

  // zero h (both buffers), c, and barrier counters each launch
  hipMemsetAsync(hb, 0, 266240, stream);

  phaseA_mfma<<<dim3(16, 64), 256, 0, stream>>>(x, wih, bih, bhh, Gb);
  lstm_persist<<<256, 256, 0, stream>>>(whh, Gb, lengths, hb, cb, hf, bar);
  finalK<<<BB, 128, 0, stream>>>(hf, who, bho, out);
}

// Round 3
// 506.144 us; speedup vs baseline: 5.8714x; 5.8714x over previous
//
#include <hip/hip_runtime.h>
#include <math.h>

#define TT 64
#define BB 64
#define DD 512
#define HH 512
#define G4 2048
#define OO 128

typedef unsigned short us16;
typedef __attribute__((ext_vector_type(8))) short bf16x8;
typedef __attribute__((ext_vector_type(4))) float f32x4;

__device__ __forceinline__ unsigned pk_bf16(float lo, float hi) {
  unsigned r;
  asm volatile("v_cvt_pk_bf16_f32 %0, %1, %2" : "=v"(r) : "v"(lo), "v"(hi));
  return r;
}

__device__ __forceinline__ float sigm(float v) { return 1.f / (1.f + expf(-v)); }

// coherent (LLC-direct) accesses for cross-block data
__device__ __forceinline__ uint4 load_b128_cc(const void* p) {
  uint4 r;
  asm volatile("global_load_dwordx4 %0, %1, off sc0 sc1" : "=v"(r) : "v"(p));
  return r;
}
__device__ __forceinline__ void store_b64_cc(void* p, uint2 v) {
  asm volatile("global_store_dwordx2 %0, %1, off sc0 sc1" ::"v"(p), "v"(v) : "memory");
}

// ============================================================================
// Phase A: G[t,b,j] = x_t @ Wih_t^T + b_ih + b_hh   via bf16 MFMA  (unchanged)
// ============================================================================
__global__ __launch_bounds__(256) void phaseA_mfma(
    const float* __restrict__ x, const float* __restrict__ wih,
    const float* __restrict__ bih, const float* __restrict__ bhh,
    float* __restrict__ Gb) {
  __shared__ us16 xa[2][64][64];
  __shared__ us16 wbuf[2][128][64];
  const int tid = threadIdx.x;
  const int t = blockIdx.y;
  const int j0 = blockIdx.x * 128;
  const int wv = tid >> 6, lane = tid & 63;
  const int wm = wv & 1, wn = wv >> 1;
  const float* xb = x + (size_t)t * (BB * DD);
  const float* wg = wih + (size_t)t * (G4 * DD) + (size_t)j0 * DD;

  float4 xr[2][2], wr[4][2];
  int xrow[2], xc[2], wrow[4], wc[4];
#pragma unroll
  for (int i = 0; i < 2; i++) { int cid = tid + i * 256; xrow[i] = cid >> 3; xc[i] = cid & 7; }
#pragma unroll
  for (int i = 0; i < 4; i++) { int cid = tid + i * 256; wrow[i] = cid >> 3; wc[i] = cid & 7; }

  auto loadx = [&](int k0) {
#pragma unroll
    for (int i = 0; i < 2; i++) {
      const float* p = xb + xrow[i] * DD + k0 + xc[i] * 8;
      xr[i][0] = *(const float4*)p; xr[i][1] = *(const float4*)(p + 4);
    }
  };
  auto loadw = [&](int k0) {
#pragma unroll
    for (int i = 0; i < 4; i++) {
      const float* p = wg + (size_t)wrow[i] * DD + k0 + wc[i] * 8;
      wr[i][0] = *(const float4*)p; wr[i][1] = *(const float4*)(p + 4);
    }
  };
  auto store = [&](int buf) {
#pragma unroll
    for (int i = 0; i < 2; i++) {
      uint4 u;
      u.x = pk_bf16(xr[i][0].x, xr[i][0].y); u.y = pk_bf16(xr[i][0].z, xr[i][0].w);
      u.z = pk_bf16(xr[i][1].x, xr[i][1].y); u.w = pk_bf16(xr[i][1].z, xr[i][1].w);
      int p = xc[i] ^ (xrow[i] & 7);
      *(uint4*)&xa[buf][xrow[i]][p * 8] = u;
    }
#pragma unroll
    for (int i = 0; i < 4; i++) {
      uint4 u;
      u.x = pk_bf16(wr[i][0].x, wr[i][0].y); u.y = pk_bf16(wr[i][0].z, wr[i][0].w);
      u.z = pk_bf16(wr[i][1].x, wr[i][1].y); u.w = pk_bf16(wr[i][1].z, wr[i][1].w);
      int p = wc[i] ^ (wrow[i] & 7);
      *(uint4*)&wbuf[buf][wrow[i]][p * 8] = u;
    }
  };

  loadx(0); loadw(0); store(0);
  __syncthreads();

  f32x4 zero = {0.f, 0.f, 0.f, 0.f};
  f32x4 acc[2][4];
#pragma unroll
  for (int mt = 0; mt < 2; mt++)
#pragma unroll
    for (int nt = 0; nt < 4; nt++) acc[mt][nt] = zero;

  for (int s = 0; s < 8; s++) {
    const int nb = s & 1;
    if (s < 7) { loadx((s + 1) * 64); loadw((s + 1) * 64); }
#pragma unroll
    for (int ks = 0; ks < 2; ks++) {
      const int cc = ks * 4 + (lane >> 4);
      bf16x8 a[2], b[4];
#pragma unroll
      for (int mt = 0; mt < 2; mt++) {
        int r = wm * 32 + mt * 16 + (lane & 15);
        a[mt] = *(const bf16x8*)&xa[nb][r][(cc ^ (r & 7)) * 8];
      }
#pragma unroll
      for (int nt = 0; nt < 4; nt++) {
        int r = wn * 64 + nt * 16 + (lane & 15);
        b[nt] = *(const bf16x8*)&wbuf[nb][r][(cc ^ (r & 7)) * 8];
      }
#pragma unroll
      for (int mt = 0; mt < 2; mt++)
#pragma unroll
        for (int nt = 0; nt < 4; nt++)
          acc[mt][nt] = __builtin_amdgcn_mfma_f32_16x16x32_bf16(a[mt], b[nt], acc[mt][nt], 0, 0, 0);
    }
    __syncthreads();
    if (s < 7) store(nb ^ 1);
    __syncthreads();
  }

  float bias[4]; int jn[4];
#pragma unroll
  for (int nt = 0; nt < 4; nt++) {
    jn[nt] = j0 + wn * 64 + nt * 16 + (lane & 15);
    bias[nt] = bih[t * G4 + jn[nt]] + bhh[t * G4 + jn[nt]];
  }
#pragma unroll
  for (int mt = 0; mt < 2; mt++)
#pragma unroll
    for (int nt = 0; nt < 4; nt++)
#pragma unroll
      for (int e = 0; e < 4; e++) {
        int brow = wm * 32 + mt * 16 + (lane >> 4) * 4 + e;
        Gb[((size_t)t * BB + brow) * G4 + jn[nt]] = acc[mt][nt][e] + bias[nt];
      }
}

// ============================================================================
// Persistent LSTM stepper: 256 blocks (bh = bid&1, ug = bid>>1 -> units ug*4..+3),
// 256 threads = 4 waves: (wm = wv&1 -> batch-16-half, kq = wv>>1 -> k-256-half).
// h lives in global in FRAGMENT-ORDER layout (bf16, 2-slot ping-pong), accessed
// only via sc0/sc1 (LLC-coherent) ops. No fences anywhere in the loop.
// Barrier: flag-store per block -> checker wave (block0,wv1) -> one 'go' word.
// ============================================================================
__global__ __launch_bounds__(256, 1) void lstm_persist(
    const float* __restrict__ whh, const float* __restrict__ Gb,
    const int* __restrict__ lengths, us16* __restrict__ hb,
    float* __restrict__ cbuf, float* __restrict__ hf,
    unsigned* __restrict__ flags) {
  __shared__ float gm[2][16][36];

  const int tid = threadIdx.x, bid = blockIdx.x;
  const int bh = bid & 1, ug = bid >> 1;
  const int wv = tid >> 6, lane = tid & 63;
  const int wm = wv & 1, kq = wv >> 1;
  const int l15 = lane & 15, klg = lane >> 4;
  unsigned* go = flags + 320;

  // B-fragment source row in Whh: ri = l15 -> gate q = ri>>2, unit u = ri&3
  const size_t jrow = (size_t)((l15 >> 2) * 512 + ug * 4 + (l15 & 3));

  float4 pf[8][2];  // W(t+next) fp32 prefetch
  auto prefW = [&](int tt) {
    const float* wt = whh + (size_t)tt * (G4 * HH) + jrow * HH;
#pragma unroll
    for (int s = 0; s < 8; s++) {
      const float* p = wt + (size_t)(kq * 32 + s * 4 + klg) * 8;
      pf[s][0] = *(const float4*)p;
      pf[s][1] = *(const float4*)(p + 4);
    }
  };
  bf16x8 wfrag[8];
  auto cvtW = [&]() {
#pragma unroll
    for (int s = 0; s < 8; s++) {
      uint4 u;
      u.x = pk_bf16(pf[s][0].x, pf[s][0].y); u.y = pk_bf16(pf[s][0].z, pf[s][0].w);
      u.z = pk_bf16(pf[s][1].x, pf[s][1].y); u.w = pk_bf16(pf[s][1].z, pf[s][1].w);
      wfrag[s] = __builtin_bit_cast(bf16x8, u);
    }
  };

  f32x4 gpre[4];  // Gb prefetch (wave0 lanes 0..31 only)
  auto prefG = [&](int tt) {
    if (tid < 32) {
      const float* gbp = &Gb[((size_t)tt * BB + bh * 32 + tid) * G4 + ug * 4];
#pragma unroll
      for (int q = 0; q < 4; q++) gpre[q] = *(const f32x4*)(gbp + q * 512);
    }
  };

  // h-store address for epilogue (thread tid<32 owns row=tid, units ug*4..+3)
  const int cch = ug >> 1;
  const int kqd = cch >> 5, rem = cch & 31, sd = rem >> 2, klgd = rem & 3;
  const int wmd = (tid & 31) >> 4;
  const int laned = klgd * 16 + (tid & 15);
  const int wvd = kqd * 2 + wmd;
  const size_t hst_off =
      (size_t)bh * 32768 + ((size_t)(wvd * 8 + sd) * 64 + laned) * 16 + (size_t)(ug & 1) * 8;

  const int mylen = (tid < 32) ? lengths[bh * 32 + tid] : -2;

  prefW(0);
  prefG(0);

  for (int t = 0; t < TT; t++) {
    if (t > 0) {
      if (tid == 0) {
        while (__hip_atomic_load(go, __ATOMIC_RELAXED, __HIP_MEMORY_SCOPE_AGENT) < (unsigned)t)
          __builtin_amdgcn_s_sleep(4);
      }
      __syncthreads();
    }

    // issue A-fragment loads (h, LLC-coherent, fully coalesced 16B/lane)
    uint4 hfrag[8];
    {
      const char* base = (const char*)hb + (size_t)(t & 1) * 65536 + (size_t)bh * 32768 +
                         ((size_t)(wv * 8) * 64 + lane) * 16;
#pragma unroll
      for (int s = 0; s < 8; s++)
        hfrag[s] = load_b128_cc(base + (size_t)s * 1024);
    }

    cvtW();  // convert W(t) prefetch -> fragments while h loads are in flight

    f32x4 gcur[4];
    if (tid < 32) {
#pragma unroll
      for (int q = 0; q < 4; q++) gcur[q] = gpre[q];
    }

    asm volatile("s_waitcnt vmcnt(0)" ::: "memory");
    __builtin_amdgcn_sched_barrier(0);

    f32x4 acc = {0.f, 0.f, 0.f, 0.f};
#pragma unroll
    for (int s = 0; s < 8; s++)
      acc = __builtin_amdgcn_mfma_f32_16x16x32_bf16(__builtin_bit_cast(bf16x8, hfrag[s]),
                                                    wfrag[s], acc, 0, 0, 0);
    *(f32x4*)&gm[kq][l15][wm * 16 + klg * 4] = acc;

    if (t + 1 < TT) { prefW(t + 1); prefG(t + 1); }  // overlap epilogue + barrier

    __syncthreads();

    if (tid < 32) {
      const int bg = bh * 32 + tid;
      f32x4 cv = *(const f32x4*)&cbuf[(size_t)bg * HH + ug * 4];
      float hvv[4];
#pragma unroll
      for (int u = 0; u < 4; u++) {
        float vi = gcur[0][u] + gm[0][0 + u][tid] + gm[1][0 + u][tid];
        float vf = gcur[1][u] + gm[0][4 + u][tid] + gm[1][4 + u][tid];
        float vg = gcur[2][u] + gm[0][8 + u][tid] + gm[1][8 + u][tid];
        float vo = gcur[3][u] + gm[0][12 + u][tid] + gm[1][12 + u][tid];
        float cn = sigm(vf) * cv[u] + sigm(vi) * tanhf(vg);
        cv[u] = cn;
        hvv[u] = sigm(vo) * tanhf(cn);
      }
      *(f32x4*)&cbuf[(size_t)bg * HH + ug * 4] = cv;
      uint2 hu;
      hu.x = pk_bf16(hvv[0], hvv[1]);
      hu.y = pk_bf16(hvv[2], hvv[3]);
      store_b64_cc((char*)hb + (size_t)((t + 1) & 1) * 65536 + hst_off, hu);
      if (mylen - 1 == t) {
        f32x4 hv4 = {hvv[0], hvv[1], hvv[2], hvv[3]};
        *(f32x4*)&hf[(size_t)bg * HH + ug * 4] = hv4;
      }
      asm volatile("s_waitcnt vmcnt(0)" ::: "memory");
      if (tid == 0)
        __hip_atomic_store(&flags[bid], (unsigned)(t + 1), __ATOMIC_RELAXED,
                           __HIP_MEMORY_SCOPE_AGENT);
    }

    if (bid == 0 && wv == 1) {  // checker wave
      const unsigned tgt = (unsigned)(t + 1);
      while (true) {
        bool ok = true;
#pragma unroll
        for (int i = 0; i < 4; i++) {
          unsigned f = __hip_atomic_load(&flags[lane + i * 64], __ATOMIC_RELAXED,
                                         __HIP_MEMORY_SCOPE_AGENT);
          ok = ok && (f >= tgt);
        }
        if (__all(ok)) break;
        __builtin_amdgcn_s_sleep(2);
      }
      if (lane == 0)
        __hip_atomic_store(go, tgt, __ATOMIC_RELAXED, __HIP_MEMORY_SCOPE_AGENT);
    }
  }
}

// ============================================================================
// Final: logits = hf @ w_ho^T + b_ho, then log_softmax
// ============================================================================
__global__ __launch_bounds__(128) void finalK(const float* __restrict__ hf,
                                              const float* __restrict__ who,
                                              const float* __restrict__ bho,
                                              float* __restrict__ out) {
  int b = blockIdx.x, o = threadIdx.x;
  const float* h = hf + b * HH;
  const float* w = who + o * HH;
  float s = bho[o];
#pragma unroll 4
  for (int k = 0; k < HH; k += 4) {
    float4 hv = *(const float4*)(h + k);
    float4 wv = *(const float4*)(w + k);
    s += hv.x * wv.x + hv.y * wv.y + hv.z * wv.z + hv.w * wv.w;
  }
  __shared__ float red[2];
  __shared__ float red2[2];
  float m = s;
#pragma unroll
  for (int msk = 32; msk; msk >>= 1) m = fmaxf(m, __shfl_xor(m, msk));
  int wave = o >> 6;
  if ((o & 63) == 0) red[wave] = m;
  __syncthreads();
  m = fmaxf(red[0], red[1]);
  float e = expf(s - m);
#pragma unroll
  for (int msk = 32; msk; msk >>= 1) e += __shfl_xor(e, msk);
  if ((o & 63) == 0) red2[wave] = e;
  __syncthreads();
  float sum = red2[0] + red2[1];
  out[b * OO + o] = (s - m) - logf(sum);
}

extern "C" void kernel_launch(void* const* d_in, const int* in_sizes, int n_in,
                              void* d_out, int out_size, void* d_ws, size_t ws_size,
                              hipStream_t stream) {
  const float* x = (const float*)d_in[0];
  const float* wih = (const float*)d_in[1];
  const float* whh = (const float*)d_in[2];
  const float* bih = (const float*)d_in[3];
  const float* bhh = (const float*)d_in[4];
  const float* who = (const float*)d_in[5];
  const float* bho = (const float*)d_in[6];
  const int* lengths = (const int*)d_in[7];
  float* out = (float*)d_out;

  char* ws = (char*)d_ws;
  float* Gb = (float*)ws;                                 // 33,554,432 B
  us16* hb = (us16*)(ws + 33554432);                      // 131,072 B (2 slots, frag layout)
  float* cb = (float*)(ws + 33554432 + 131072);           // 131,072 B
  unsigned* flags = (unsigned*)(ws + 33554432 + 262144);  // 2,048 B (flags + go)
  float* hf = (float*)(ws + 33554432 + 264192);           // 131,072 B

  hipMemsetAsync(hb, 0, 264192, stream);  // h slots, c, flags/go

  phaseA_mfma<<<dim3(16, 64), 256, 0, stream>>>(x, wih, bih, bhh, Gb);
  lstm_persist<<<256, 256, 0, stream>>>(whh, Gb, lengths, hb, cb, hf, flags);
  finalK<<<BB, 128, 0, stream>>>(hf, who, bho, out);
}

// Round 4
// 346.367 us; speedup vs baseline: 8.5798x; 1.4613x over previous
//
#include <hip/hip_runtime.h>
#include <math.h>

#define TT 64
#define BB 64
#define DD 512
#define HH 512
#define G4 2048
#define OO 128

typedef unsigned short us16;
typedef __attribute__((ext_vector_type(8))) short bf16x8;
typedef __attribute__((ext_vector_type(4))) float f32x4;

__device__ __forceinline__ unsigned pk_bf16(float lo, float hi) {
  unsigned r;
  asm volatile("v_cvt_pk_bf16_f32 %0, %1, %2" : "=v"(r) : "v"(lo), "v"(hi));
  return r;
}

__device__ __forceinline__ float sigm(float v) { return 1.f / (1.f + expf(-v)); }

// coherent (LLC-direct) accesses for cross-block data
__device__ __forceinline__ uint4 load_b128_cc(const void* p) {
  uint4 r;
  asm volatile("global_load_dwordx4 %0, %1, off sc0 sc1" : "=v"(r) : "v"(p));
  return r;
}
__device__ __forceinline__ void store_b64_cc(void* p, uint2 v) {
  asm volatile("global_store_dwordx2 %0, %1, off sc0 sc1" ::"v"(p), "v"(v) : "memory");
}

// ============================================================================
// Phase A: G[t,b,j] = x_t @ Wih_t^T + b_ih + b_hh   via bf16 MFMA  (unchanged)
// ============================================================================
__global__ __launch_bounds__(256) void phaseA_mfma(
    const float* __restrict__ x, const float* __restrict__ wih,
    const float* __restrict__ bih, const float* __restrict__ bhh,
    float* __restrict__ Gb) {
  __shared__ us16 xa[2][64][64];
  __shared__ us16 wbuf[2][128][64];
  const int tid = threadIdx.x;
  const int t = blockIdx.y;
  const int j0 = blockIdx.x * 128;
  const int wv = tid >> 6, lane = tid & 63;
  const int wm = wv & 1, wn = wv >> 1;
  const float* xb = x + (size_t)t * (BB * DD);
  const float* wg = wih + (size_t)t * (G4 * DD) + (size_t)j0 * DD;

  float4 xr[2][2], wr[4][2];
  int xrow[2], xc[2], wrow[4], wc[4];
#pragma unroll
  for (int i = 0; i < 2; i++) { int cid = tid + i * 256; xrow[i] = cid >> 3; xc[i] = cid & 7; }
#pragma unroll
  for (int i = 0; i < 4; i++) { int cid = tid + i * 256; wrow[i] = cid >> 3; wc[i] = cid & 7; }

  auto loadx = [&](int k0) {
#pragma unroll
    for (int i = 0; i < 2; i++) {
      const float* p = xb + xrow[i] * DD + k0 + xc[i] * 8;
      xr[i][0] = *(const float4*)p; xr[i][1] = *(const float4*)(p + 4);
    }
  };
  auto loadw = [&](int k0) {
#pragma unroll
    for (int i = 0; i < 4; i++) {
      const float* p = wg + (size_t)wrow[i] * DD + k0 + wc[i] * 8;
      wr[i][0] = *(const float4*)p; wr[i][1] = *(const float4*)(p + 4);
    }
  };
  auto store = [&](int buf) {
#pragma unroll
    for (int i = 0; i < 2; i++) {
      uint4 u;
      u.x = pk_bf16(xr[i][0].x, xr[i][0].y); u.y = pk_bf16(xr[i][0].z, xr[i][0].w);
      u.z = pk_bf16(xr[i][1].x, xr[i][1].y); u.w = pk_bf16(xr[i][1].z, xr[i][1].w);
      int p = xc[i] ^ (xrow[i] & 7);
      *(uint4*)&xa[buf][xrow[i]][p * 8] = u;
    }
#pragma unroll
    for (int i = 0; i < 4; i++) {
      uint4 u;
      u.x = pk_bf16(wr[i][0].x, wr[i][0].y); u.y = pk_bf16(wr[i][0].z, wr[i][0].w);
      u.z = pk_bf16(wr[i][1].x, wr[i][1].y); u.w = pk_bf16(wr[i][1].z, wr[i][1].w);
      int p = wc[i] ^ (wrow[i] & 7);
      *(uint4*)&wbuf[buf][wrow[i]][p * 8] = u;
    }
  };

  loadx(0); loadw(0); store(0);
  __syncthreads();

  f32x4 zero = {0.f, 0.f, 0.f, 0.f};
  f32x4 acc[2][4];
#pragma unroll
  for (int mt = 0; mt < 2; mt++)
#pragma unroll
    for (int nt = 0; nt < 4; nt++) acc[mt][nt] = zero;

  for (int s = 0; s < 8; s++) {
    const int nb = s & 1;
    if (s < 7) { loadx((s + 1) * 64); loadw((s + 1) * 64); }
#pragma unroll
    for (int ks = 0; ks < 2; ks++) {
      const int cc = ks * 4 + (lane >> 4);
      bf16x8 a[2], b[4];
#pragma unroll
      for (int mt = 0; mt < 2; mt++) {
        int r = wm * 32 + mt * 16 + (lane & 15);
        a[mt] = *(const bf16x8*)&xa[nb][r][(cc ^ (r & 7)) * 8];
      }
#pragma unroll
      for (int nt = 0; nt < 4; nt++) {
        int r = wn * 64 + nt * 16 + (lane & 15);
        b[nt] = *(const bf16x8*)&wbuf[nb][r][(cc ^ (r & 7)) * 8];
      }
#pragma unroll
      for (int mt = 0; mt < 2; mt++)
#pragma unroll
        for (int nt = 0; nt < 4; nt++)
          acc[mt][nt] = __builtin_amdgcn_mfma_f32_16x16x32_bf16(a[mt], b[nt], acc[mt][nt], 0, 0, 0);
    }
    __syncthreads();
    if (s < 7) store(nb ^ 1);
    __syncthreads();
  }

  float bias[4]; int jn[4];
#pragma unroll
  for (int nt = 0; nt < 4; nt++) {
    jn[nt] = j0 + wn * 64 + nt * 16 + (lane & 15);
    bias[nt] = bih[t * G4 + jn[nt]] + bhh[t * G4 + jn[nt]];
  }
#pragma unroll
  for (int mt = 0; mt < 2; mt++)
#pragma unroll
    for (int nt = 0; nt < 4; nt++)
#pragma unroll
      for (int e = 0; e < 4; e++) {
        int brow = wm * 32 + mt * 16 + (lane >> 4) * 4 + e;
        Gb[((size_t)t * BB + brow) * G4 + jn[nt]] = acc[mt][nt][e] + bias[nt];
      }
}

// ============================================================================
// Persistent LSTM stepper: 256 blocks (bh = bid&1, ug = bid>>1 -> units ug*4..+3),
// 256 threads = 4 waves: (wm = wv&1 -> batch-16-half, kq = wv>>1 -> k-256-half).
// h in global FRAGMENT-ORDER layout (bf16, 2-slot ping-pong), sc0/sc1 only.
// Barrier: per-block flag store -> every block's wave0 polls the 128 flags of
// its batch-half directly (flat, no checker hop). W(t+1)/G(t+1) prefetch is
// issued AFTER the flag store so the epilogue's vmcnt(0) never drains it.
// ============================================================================
__global__ __launch_bounds__(256, 1) void lstm_persist(
    const float* __restrict__ whh, const float* __restrict__ Gb,
    const int* __restrict__ lengths, us16* __restrict__ hb,
    float* __restrict__ cbuf, float* __restrict__ hf,
    unsigned* __restrict__ flags) {
  __shared__ float gm[2][16][36];

  const int tid = threadIdx.x, bid = blockIdx.x;
  const int bh = bid & 1, ug = bid >> 1;
  const int wv = tid >> 6, lane = tid & 63;
  const int wm = wv & 1, kq = wv >> 1;
  const int l15 = lane & 15, klg = lane >> 4;

  // B-fragment source row in Whh: ri = l15 -> gate q = ri>>2, unit u = ri&3
  const size_t jrow = (size_t)((l15 >> 2) * 512 + ug * 4 + (l15 & 3));

  float4 pf[8][2];  // W(t+next) fp32 prefetch
  auto prefW = [&](int tt) {
    const float* wt = whh + (size_t)tt * (G4 * HH) + jrow * HH;
#pragma unroll
    for (int s = 0; s < 8; s++) {
      const float* p = wt + (size_t)(kq * 32 + s * 4 + klg) * 8;
      pf[s][0] = *(const float4*)p;
      pf[s][1] = *(const float4*)(p + 4);
    }
  };
  bf16x8 wfrag[8];
  auto cvtW = [&]() {
#pragma unroll
    for (int s = 0; s < 8; s++) {
      uint4 u;
      u.x = pk_bf16(pf[s][0].x, pf[s][0].y); u.y = pk_bf16(pf[s][0].z, pf[s][0].w);
      u.z = pk_bf16(pf[s][1].x, pf[s][1].y); u.w = pk_bf16(pf[s][1].z, pf[s][1].w);
      wfrag[s] = __builtin_bit_cast(bf16x8, u);
    }
  };

  f32x4 gpre[4];  // Gb prefetch (wave0 lanes 0..31 only)
  auto prefG = [&](int tt) {
    if (tid < 32) {
      const float* gbp = &Gb[((size_t)tt * BB + bh * 32 + tid) * G4 + ug * 4];
#pragma unroll
      for (int q = 0; q < 4; q++) gpre[q] = *(const f32x4*)(gbp + q * 512);
    }
  };

  // h-store address for epilogue (thread tid<32 owns row=tid, units ug*4..+3)
  const int cch = ug >> 1;
  const int kqd = cch >> 5, rem = cch & 31, sd = rem >> 2, klgd = rem & 3;
  const int wmd = (tid & 31) >> 4;
  const int laned = klgd * 16 + (tid & 15);
  const int wvd = kqd * 2 + wmd;
  const size_t hst_off =
      (size_t)bh * 32768 + ((size_t)(wvd * 8 + sd) * 64 + laned) * 16 + (size_t)(ug & 1) * 8;

  // poll indices: the 128 producer flags of this batch-half (padded 4 words apart)
  const int pidx0 = (2 * lane + bh) * 4;
  const int pidx1 = (2 * (lane + 64) + bh) * 4;

  const int mylen = (tid < 32) ? lengths[bh * 32 + tid] : -2;

  prefW(0);
  prefG(0);

  for (int t = 0; t < TT; t++) {
    if (t > 0) {
      if (wv == 0) {
        const unsigned tgt = (unsigned)t;
        while (true) {
          unsigned f0 = __hip_atomic_load(&flags[pidx0], __ATOMIC_RELAXED,
                                          __HIP_MEMORY_SCOPE_AGENT);
          unsigned f1 = __hip_atomic_load(&flags[pidx1], __ATOMIC_RELAXED,
                                          __HIP_MEMORY_SCOPE_AGENT);
          if (__all(f0 >= tgt && f1 >= tgt)) break;
          __builtin_amdgcn_s_sleep(1);
        }
      }
      __syncthreads();
    }

    // issue A-fragment loads (h, LLC-coherent, fully coalesced 16B/lane)
    uint4 hfrag[8];
    {
      const char* base = (const char*)hb + (size_t)(t & 1) * 65536 + (size_t)bh * 32768 +
                         ((size_t)(wv * 8) * 64 + lane) * 16;
#pragma unroll
      for (int s = 0; s < 8; s++)
        hfrag[s] = load_b128_cc(base + (size_t)s * 1024);
    }

    cvtW();  // convert W(t) prefetch -> fragments while h loads are in flight

    f32x4 gcur[4];
    if (tid < 32) {
#pragma unroll
      for (int q = 0; q < 4; q++) gcur[q] = gpre[q];
    }

    asm volatile("s_waitcnt vmcnt(0)" ::: "memory");
    __builtin_amdgcn_sched_barrier(0);

    f32x4 acc = {0.f, 0.f, 0.f, 0.f};
#pragma unroll
    for (int s = 0; s < 8; s++)
      acc = __builtin_amdgcn_mfma_f32_16x16x32_bf16(__builtin_bit_cast(bf16x8, hfrag[s]),
                                                    wfrag[s], acc, 0, 0, 0);
    *(f32x4*)&gm[kq][l15][wm * 16 + klg * 4] = acc;

    __syncthreads();

    if (tid < 32) {
      const int bg = bh * 32 + tid;
      f32x4 cv = *(const f32x4*)&cbuf[(size_t)bg * HH + ug * 4];
      float hvv[4];
#pragma unroll
      for (int u = 0; u < 4; u++) {
        float vi = gcur[0][u] + gm[0][0 + u][tid] + gm[1][0 + u][tid];
        float vf = gcur[1][u] + gm[0][4 + u][tid] + gm[1][4 + u][tid];
        float vg = gcur[2][u] + gm[0][8 + u][tid] + gm[1][8 + u][tid];
        float vo = gcur[3][u] + gm[0][12 + u][tid] + gm[1][12 + u][tid];
        float cn = sigm(vf) * cv[u] + sigm(vi) * tanhf(vg);
        cv[u] = cn;
        hvv[u] = sigm(vo) * tanhf(cn);
      }
      *(f32x4*)&cbuf[(size_t)bg * HH + ug * 4] = cv;
      uint2 hu;
      hu.x = pk_bf16(hvv[0], hvv[1]);
      hu.y = pk_bf16(hvv[2], hvv[3]);
      store_b64_cc((char*)hb + (size_t)((t + 1) & 1) * 65536 + hst_off, hu);
      if (mylen - 1 == t) {
        f32x4 hv4 = {hvv[0], hvv[1], hvv[2], hvv[3]};
        *(f32x4*)&hf[(size_t)bg * HH + ug * 4] = hv4;
      }
      asm volatile("s_waitcnt vmcnt(0)" ::: "memory");  // only epilogue's own stores
      if (tid == 0)
        __hip_atomic_store(&flags[bid * 4], (unsigned)(t + 1), __ATOMIC_RELAXED,
                           __HIP_MEMORY_SCOPE_AGENT);
    }

    // W/G prefetch for t+1 issued AFTER the flag release: streams from HBM
    // during the barrier wait, never drained by any critical-path waitcnt.
    if (t + 1 < TT) { prefW(t + 1); prefG(t + 1); }
  }
}

// ============================================================================
// Final: logits = hf @ w_ho^T + b_ho, then log_softmax
// ============================================================================
__global__ __launch_bounds__(128) void finalK(const float* __restrict__ hf,
                                              const float* __restrict__ who,
                                              const float* __restrict__ bho,
                                              float* __restrict__ out) {
  int b = blockIdx.x, o = threadIdx.x;
  const float* h = hf + b * HH;
  const float* w = who + o * HH;
  float s = bho[o];
#pragma unroll 4
  for (int k = 0; k < HH; k += 4) {
    float4 hv = *(const float4*)(h + k);
    float4 wv = *(const float4*)(w + k);
    s += hv.x * wv.x + hv.y * wv.y + hv.z * wv.z + hv.w * wv.w;
  }
  __shared__ float red[2];
  __shared__ float red2[2];
  float m = s;
#pragma unroll
  for (int msk = 32; msk; msk >>= 1) m = fmaxf(m, __shfl_xor(m, msk));
  int wave = o >> 6;
  if ((o & 63) == 0) red[wave] = m;
  __syncthreads();
  m = fmaxf(red[0], red[1]);
  float e = expf(s - m);
#pragma unroll
  for (int msk = 32; msk; msk >>= 1) e += __shfl_xor(e, msk);
  if ((o & 63) == 0) red2[wave] = e;
  __syncthreads();
  float sum = red2[0] + red2[1];
  out[b * OO + o] = (s - m) - logf(sum);
}

extern "C" void kernel_launch(void* const* d_in, const int* in_sizes, int n_in,
                              void* d_out, int out_size, void* d_ws, size_t ws_size,
                              hipStream_t stream) {
  const float* x = (const float*)d_in[0];
  const float* wih = (const float*)d_in[1];
  const float* whh = (const float*)d_in[2];
  const float* bih = (const float*)d_in[3];
  const float* bhh = (const float*)d_in[4];
  const float* who = (const float*)d_in[5];
  const float* bho = (const float*)d_in[6];
  const int* lengths = (const int*)d_in[7];
  float* out = (float*)d_out;

  char* ws = (char*)d_ws;
  float* Gb = (float*)ws;                                 // 33,554,432 B
  us16* hb = (us16*)(ws + 33554432);                      // 131,072 B (2 slots, frag layout)
  float* cb = (float*)(ws + 33554432 + 131072);           // 131,072 B
  unsigned* flags = (unsigned*)(ws + 33554432 + 262144);  // 8,192 B (256 flags, 16B apart)
  float* hf = (float*)(ws + 33554432 + 270336);           // 131,072 B

  hipMemsetAsync(hb, 0, 270336, stream);  // h slots, c, flags

  phaseA_mfma<<<dim3(16, 64), 256, 0, stream>>>(x, wih, bih, bhh, Gb);
  lstm_persist<<<256, 256, 0, stream>>>(whh, Gb, lengths, hb, cb, hf, flags);
  finalK<<<BB, 128, 0, stream>>>(hf, who, bho, out);
}

// Round 6
// 342.886 us; speedup vs baseline: 8.6669x; 1.0102x over previous
//
#include <hip/hip_runtime.h>
#include <math.h>

#define TT 64
#define BB 64
#define DD 512
#define HH 512
#define G4 2048
#define OO 128

typedef unsigned short us16;
typedef __attribute__((ext_vector_type(8))) short bf16x8;
typedef __attribute__((ext_vector_type(4))) float f32x4;
typedef __attribute__((ext_vector_type(4))) unsigned u32x4;

__device__ __forceinline__ unsigned pk_bf16(float lo, float hi) {
  unsigned r;
  asm volatile("v_cvt_pk_bf16_f32 %0, %1, %2" : "=v"(r) : "v"(lo), "v"(hi));
  return r;
}

__device__ __forceinline__ float sigm(float v) { return 1.f / (1.f + expf(-v)); }

// coherent (LLC-direct) accesses for cross-block data
__device__ __forceinline__ u32x4 load_b128_cc(const void* p) {
  u32x4 r;
  asm volatile("global_load_dwordx4 %0, %1, off sc0 sc1" : "=v"(r) : "v"(p));
  return r;
}
__device__ __forceinline__ void store_b128_cc(void* p, u32x4 v) {
  asm volatile("global_store_dwordx4 %0, %1, off sc0 sc1" ::"v"(p), "v"(v) : "memory");
}

// ============================================================================
// Phase A: G[t,b,j] = x_t @ Wih_t^T + b_ih + b_hh   via bf16 MFMA  (unchanged)
// ============================================================================
__global__ __launch_bounds__(256) void phaseA_mfma(
    const float* __restrict__ x, const float* __restrict__ wih,
    const float* __restrict__ bih, const float* __restrict__ bhh,
    float* __restrict__ Gb) {
  __shared__ us16 xa[2][64][64];
  __shared__ us16 wbuf[2][128][64];
  const int tid = threadIdx.x;
  const int t = blockIdx.y;
  const int j0 = blockIdx.x * 128;
  const int wv = tid >> 6, lane = tid & 63;
  const int wm = wv & 1, wn = wv >> 1;
  const float* xb = x + (size_t)t * (BB * DD);
  const float* wg = wih + (size_t)t * (G4 * DD) + (size_t)j0 * DD;

  float4 xr[2][2], wr[4][2];
  int xrow[2], xc[2], wrow[4], wc[4];
#pragma unroll
  for (int i = 0; i < 2; i++) { int cid = tid + i * 256; xrow[i] = cid >> 3; xc[i] = cid & 7; }
#pragma unroll
  for (int i = 0; i < 4; i++) { int cid = tid + i * 256; wrow[i] = cid >> 3; wc[i] = cid & 7; }

  auto loadx = [&](int k0) {
#pragma unroll
    for (int i = 0; i < 2; i++) {
      const float* p = xb + xrow[i] * DD + k0 + xc[i] * 8;
      xr[i][0] = *(const float4*)p; xr[i][1] = *(const float4*)(p + 4);
    }
  };
  auto loadw = [&](int k0) {
#pragma unroll
    for (int i = 0; i < 4; i++) {
      const float* p = wg + (size_t)wrow[i] * DD + k0 + wc[i] * 8;
      wr[i][0] = *(const float4*)p; wr[i][1] = *(const float4*)(p + 4);
    }
  };
  auto store = [&](int buf) {
#pragma unroll
    for (int i = 0; i < 2; i++) {
      uint4 u;
      u.x = pk_bf16(xr[i][0].x, xr[i][0].y); u.y = pk_bf16(xr[i][0].z, xr[i][0].w);
      u.z = pk_bf16(xr[i][1].x, xr[i][1].y); u.w = pk_bf16(xr[i][1].z, xr[i][1].w);
      int p = xc[i] ^ (xrow[i] & 7);
      *(uint4*)&xa[buf][xrow[i]][p * 8] = u;
    }
#pragma unroll
    for (int i = 0; i < 4; i++) {
      uint4 u;
      u.x = pk_bf16(wr[i][0].x, wr[i][0].y); u.y = pk_bf16(wr[i][0].z, wr[i][0].w);
      u.z = pk_bf16(wr[i][1].x, wr[i][1].y); u.w = pk_bf16(wr[i][1].z, wr[i][1].w);
      int p = wc[i] ^ (wrow[i] & 7);
      *(uint4*)&wbuf[buf][wrow[i]][p * 8] = u;
    }
  };

  loadx(0); loadw(0); store(0);
  __syncthreads();

  f32x4 zero = {0.f, 0.f, 0.f, 0.f};
  f32x4 acc[2][4];
#pragma unroll
  for (int mt = 0; mt < 2; mt++)
#pragma unroll
    for (int nt = 0; nt < 4; nt++) acc[mt][nt] = zero;

  for (int s = 0; s < 8; s++) {
    const int nb = s & 1;
    if (s < 7) { loadx((s + 1) * 64); loadw((s + 1) * 64); }
#pragma unroll
    for (int ks = 0; ks < 2; ks++) {
      const int cc = ks * 4 + (lane >> 4);
      bf16x8 a[2], b[4];
#pragma unroll
      for (int mt = 0; mt < 2; mt++) {
        int r = wm * 32 + mt * 16 + (lane & 15);
        a[mt] = *(const bf16x8*)&xa[nb][r][(cc ^ (r & 7)) * 8];
      }
#pragma unroll
      for (int nt = 0; nt < 4; nt++) {
        int r = wn * 64 + nt * 16 + (lane & 15);
        b[nt] = *(const bf16x8*)&wbuf[nb][r][(cc ^ (r & 7)) * 8];
      }
#pragma unroll
      for (int mt = 0; mt < 2; mt++)
#pragma unroll
        for (int nt = 0; nt < 4; nt++)
          acc[mt][nt] = __builtin_amdgcn_mfma_f32_16x16x32_bf16(a[mt], b[nt], acc[mt][nt], 0, 0, 0);
    }
    __syncthreads();
    if (s < 7) store(nb ^ 1);
    __syncthreads();
  }

  float bias[4]; int jn[4];
#pragma unroll
  for (int nt = 0; nt < 4; nt++) {
    jn[nt] = j0 + wn * 64 + nt * 16 + (lane & 15);
    bias[nt] = bih[t * G4 + jn[nt]] + bhh[t * G4 + jn[nt]];
  }
#pragma unroll
  for (int mt = 0; mt < 2; mt++)
#pragma unroll
    for (int nt = 0; nt < 4; nt++)
#pragma unroll
      for (int e = 0; e < 4; e++) {
        int brow = wm * 32 + mt * 16 + (lane >> 4) * 4 + e;
        Gb[((size_t)t * BB + brow) * G4 + jn[nt]] = acc[mt][nt][e] + bias[nt];
      }
}

// ============================================================================
// Persistent LSTM stepper: 256 blocks (bh = bid&1, ug = bid>>1 -> units ug*4..+3),
// 4 waves (wm = wv&1 -> batch-16-half, kq = wv>>1 -> k-256-half).
// h lives in global as 16B TAGGED RECORDS: [8B = 4 bf16 h][4B step tag][4B pad],
// 2-slot ping-pong, sc0/sc1 only. Publish = the data store itself (single 16B
// transaction). Consumers poll by loading their 16 records and checking tags;
// on success the h data is already in registers. No flags, no drains.
// c state in registers. Epilogue over 64 lanes (2 units each) + shfl gather.
// ============================================================================
__global__ __launch_bounds__(256, 1) void lstm_persist(
    const float* __restrict__ whh, const float* __restrict__ Gb,
    const int* __restrict__ lengths, char* __restrict__ hb,
    float* __restrict__ hf) {
  __shared__ float gm[2][16][36];

  const int tid = threadIdx.x, bid = blockIdx.x;
  const int bh = bid & 1, ug = bid >> 1;
  const int wv = tid >> 6, lane = tid & 63;
  const int wm = wv & 1, kq = wv >> 1;
  const int l15 = lane & 15, klg = lane >> 4;

  // B-fragment source row in Whh: ri = l15 -> gate q = ri>>2, unit u = ri&3
  const size_t jrow = (size_t)((l15 >> 2) * 512 + ug * 4 + (l15 & 3));

  float4 pf[8][2];  // W(t) fp32 prefetch
  auto prefW = [&](int tt) {
    const float* wt = whh + (size_t)tt * (G4 * HH) + jrow * HH;
#pragma unroll
    for (int s = 0; s < 8; s++) {
      const float* p = wt + (size_t)(kq * 32 + s * 4 + klg) * 8;
      pf[s][0] = *(const float4*)p;
      pf[s][1] = *(const float4*)(p + 4);
    }
  };
  bf16x8 wfrag[8];
  auto cvtW = [&]() {
#pragma unroll
    for (int s = 0; s < 8; s++) {
      uint4 u;
      u.x = pk_bf16(pf[s][0].x, pf[s][0].y); u.y = pk_bf16(pf[s][0].z, pf[s][0].w);
      u.z = pk_bf16(pf[s][1].x, pf[s][1].y); u.w = pk_bf16(pf[s][1].z, pf[s][1].w);
      wfrag[s] = __builtin_bit_cast(bf16x8, u);
    }
  };

  float2 gpre[4];  // Gb prefetch (wave0, 64 lanes: 2 units each)
  auto prefG = [&](int tt) {
    if (wv == 0) {
      const float* gbp =
          Gb + ((size_t)tt * BB + bh * 32 + (lane & 31)) * G4 + ug * 4 + ((lane >> 5) << 1);
#pragma unroll
      for (int q = 0; q < 4; q++) gpre[q] = *(const float2*)(gbp + q * 512);
    }
  };

  // record addresses: record (u4, m) at half_base + (u4*32 + m)*16
  // consumer: u4 = kq*64 + s*8 + klg*2 (+0/+1), m = wm*16 + l15
  const size_t cbase =
      (size_t)bh * 65536 + ((size_t)(kq * 64 + klg * 2) * 32 + wm * 16 + l15) * 16;
  // producer (wave0, lane<32): u4 = ug, m = lane
  const size_t pbase = (size_t)bh * 65536 + ((size_t)ug * 32 + (lane & 31)) * 16;

  const int mylen = (wv == 0) ? lengths[bh * 32 + (lane & 31)] : -2;
  float cst[2] = {0.f, 0.f};  // c state in registers (wave0 lanes, 2 units each)

  prefW(0);
  prefG(0);

  for (int t = 0; t < TT; t++) {
    cvtW();  // consume pf (waits its loads) -> frees fp32 W regs before record loads

    u32x4 r0[8], r1[8];
    if (t == 0) {
      u32x4 z = {0u, 0u, 0u, 0u};
#pragma unroll
      for (int s = 0; s < 8; s++) { r0[s] = z; r1[s] = z; }
    } else {
      const char* sbase = hb + (size_t)(t & 1) * 131072 + cbase;
      const unsigned tg = (unsigned)t;
      bool ok;
      do {
#pragma unroll
        for (int s = 0; s < 8; s++) {
          r0[s] = load_b128_cc(sbase + (size_t)s * 4096);
          r1[s] = load_b128_cc(sbase + (size_t)s * 4096 + 512);
        }
        asm volatile("s_waitcnt vmcnt(0)" ::: "memory");
        __builtin_amdgcn_sched_barrier(0);
        ok = true;
#pragma unroll
        for (int s = 0; s < 8; s++) ok = ok && (r0[s].z == tg) && (r1[s].z == tg);
      } while (!__all(ok));
    }

    f32x4 acc = {0.f, 0.f, 0.f, 0.f};
#pragma unroll
    for (int s = 0; s < 8; s++) {
      u32x4 fa;
      fa.x = r0[s].x; fa.y = r0[s].y; fa.z = r1[s].x; fa.w = r1[s].y;
      acc = __builtin_amdgcn_mfma_f32_16x16x32_bf16(__builtin_bit_cast(bf16x8, fa),
                                                    wfrag[s], acc, 0, 0, 0);
    }
    *(f32x4*)&gm[kq][l15][wm * 16 + klg * 4] = acc;

    __syncthreads();

    float2 gcur[4];
    if (wv == 0) {
#pragma unroll
      for (int q = 0; q < 4; q++) gcur[q] = gpre[q];
    }
    // W/G prefetch for t+1: streams during epilogue + next poll, off critical path
    if (t + 1 < TT) { prefW(t + 1); prefG(t + 1); }

    if (wv == 0) {
      const int b = lane & 31, hi = lane >> 5;
      float hv[2];
#pragma unroll
      for (int uu = 0; uu < 2; uu++) {
        const int lu = hi * 2 + uu;
        float vi = (uu ? gcur[0].y : gcur[0].x) + gm[0][0 + lu][b] + gm[1][0 + lu][b];
        float vf = (uu ? gcur[1].y : gcur[1].x) + gm[0][4 + lu][b] + gm[1][4 + lu][b];
        float vg = (uu ? gcur[2].y : gcur[2].x) + gm[0][8 + lu][b] + gm[1][8 + lu][b];
        float vo = (uu ? gcur[3].y : gcur[3].x) + gm[0][12 + lu][b] + gm[1][12 + lu][b];
        float cn = sigm(vf) * cst[uu] + sigm(vi) * tanhf(vg);
        cst[uu] = cn;
        hv[uu] = sigm(vo) * tanhf(cn);
      }
      unsigned hw = pk_bf16(hv[0], hv[1]);
      unsigned other = __shfl_xor(hw, 32);
      if (mylen - 1 == t) {
        float2 o2; o2.x = hv[0]; o2.y = hv[1];
        *(float2*)&hf[(size_t)(bh * 32 + b) * HH + ug * 4 + hi * 2] = o2;
      }
      if (hi == 0 && t + 1 < TT) {
        u32x4 rec;
        rec.x = hw; rec.y = other; rec.z = (unsigned)(t + 1); rec.w = 0u;
        store_b128_cc(hb + (size_t)((t + 1) & 1) * 131072 + pbase, rec);
      }
    }
  }
}

// ============================================================================
// Final: logits = hf @ w_ho^T + b_ho, then log_softmax
// ============================================================================
__global__ __launch_bounds__(128) void finalK(const float* __restrict__ hf,
                                              const float* __restrict__ who,
                                              const float* __restrict__ bho,
                                              float* __restrict__ out) {
  int b = blockIdx.x, o = threadIdx.x;
  const float* h = hf + b * HH;
  const float* w = who + o * HH;
  float s = bho[o];
#pragma unroll 4
  for (int k = 0; k < HH; k += 4) {
    float4 hv = *(const float4*)(h + k);
    float4 wv = *(const float4*)(w + k);
    s += hv.x * wv.x + hv.y * wv.y + hv.z * wv.z + hv.w * wv.w;
  }
  __shared__ float red[2];
  __shared__ float red2[2];
  float m = s;
#pragma unroll
  for (int msk = 32; msk; msk >>= 1) m = fmaxf(m, __shfl_xor(m, msk));
  int wave = o >> 6;
  if ((o & 63) == 0) red[wave] = m;
  __syncthreads();
  m = fmaxf(red[0], red[1]);
  float e = expf(s - m);
#pragma unroll
  for (int msk = 32; msk; msk >>= 1) e += __shfl_xor(e, msk);
  if ((o & 63) == 0) red2[wave] = e;
  __syncthreads();
  float sum = red2[0] + red2[1];
  out[b * OO + o] = (s - m) - logf(sum);
}

extern "C" void kernel_launch(void* const* d_in, const int* in_sizes, int n_in,
                              void* d_out, int out_size, void* d_ws, size_t ws_size,
                              hipStream_t stream) {
  const float* x = (const float*)d_in[0];
  const float* wih = (const float*)d_in[1];
  const float* whh = (const float*)d_in[2];
  const float* bih = (const float*)d_in[3];
  const float* bhh = (const float*)d_in[4];
  const float* who = (const float*)d_in[5];
  const float* bho = (const float*)d_in[6];
  const int* lengths = (const int*)d_in[7];
  float* out = (float*)d_out;

  char* ws = (char*)d_ws;
  float* Gb = (float*)ws;                        // 33,554,432 B
  char* hb = ws + 33554432;                      // 262,144 B (2 slots x 2 halves x 4096 records)
  float* hf = (float*)(ws + 33554432 + 262144);  // 131,072 B

  (void)hipMemsetAsync(hb, 0, 262144, stream);  // zero h values + tags in both slots

  phaseA_mfma<<<dim3(16, 64), 256, 0, stream>>>(x, wih, bih, bhh, Gb);
  lstm_persist<<<256, 256, 0, stream>>>(whh, Gb, lengths, hb, hf);
  finalK<<<BB, 128, 0, stream>>>(hf, who, bho, out);
}